// Round 1
// baseline (9510.329 us; speedup 1.0000x reference)
//
#include <hip/hip_runtime.h>
#include <cstdint>

// Problem constants: B=2, T=2048, C=1024, H=16, D=64, TOP_K=256
// feat_keep = ceil(D*min(TOP_K,T)/T) = ceil(64*256/2048) = 8
constexpr int Tn = 2048;
constexpr int Cn = 1024;
constexpr int Hn = 16;
constexpr int Dn = 64;
constexpr int Mn = 4096;          // B*T
constexpr int KKEEP = 256;        // row-wise top-k
constexpr int FKEEP = 8;          // feature top-k
constexpr unsigned U_NEG_INF = 0x007FFFFFu;  // umap(-inf)

// Order-preserving fp32 -> uint32 map (monotonic incl. +-inf; no NaNs here).
__device__ __forceinline__ unsigned umap(float f) {
    unsigned b = __float_as_uint(f);
    return (b & 0x80000000u) ? ~b : (b | 0x80000000u);
}
__device__ __forceinline__ float uunmap(unsigned u) {
    return __uint_as_float((u & 0x80000000u) ? (u ^ 0x80000000u) : ~u);
}

// ---------------------------------------------------------------------------
// fp32 GEMM: O[m][n] = sum_k A[m][k] * W[n][k]   (A: 4096x1024, W: 1024x1024)
// 128x128 tile, Kc=16, 256 threads, 8x8 microtile. blockIdx.z selects W/O.
// ---------------------------------------------------------------------------
constexpr int TM = 128, TN = 128, TK = 16;

__global__ __launch_bounds__(256)
void gemm_nt_f32(const float* __restrict__ A,
                 const float* __restrict__ W0, const float* __restrict__ W1,
                 const float* __restrict__ W2,
                 float* __restrict__ O0, float* __restrict__ O1,
                 float* __restrict__ O2)
{
    const float* Wm = (blockIdx.z == 0) ? W0 : (blockIdx.z == 1 ? W1 : W2);
    float*       O  = (blockIdx.z == 0) ? O0 : (blockIdx.z == 1 ? O1 : O2);

    __shared__ float As[TK][TM];   // [k][m]
    __shared__ float Bs[TK][TN];   // [k][n]

    const int tid = threadIdx.x;
    const int tx = tid & 15, ty = tid >> 4;
    const int m0 = blockIdx.y * TM;
    const int n0 = blockIdx.x * TN;

    float acc[8][8] = {};

    for (int k0 = 0; k0 < Cn; k0 += TK) {
        __syncthreads();
        // stage 128 rows x 16 k of A and W (2 float4 per thread each)
#pragma unroll
        for (int r = 0; r < 2; ++r) {
            const int f = tid + r * 256;      // 0..511
            const int row = f >> 2, q = f & 3;
            const float4 av = *(const float4*)&A[(size_t)(m0 + row) * Cn + k0 + q * 4];
            As[q * 4 + 0][row] = av.x; As[q * 4 + 1][row] = av.y;
            As[q * 4 + 2][row] = av.z; As[q * 4 + 3][row] = av.w;
            const float4 wv = *(const float4*)&Wm[(size_t)(n0 + row) * Cn + k0 + q * 4];
            Bs[q * 4 + 0][row] = wv.x; Bs[q * 4 + 1][row] = wv.y;
            Bs[q * 4 + 2][row] = wv.z; Bs[q * 4 + 3][row] = wv.w;
        }
        __syncthreads();
#pragma unroll
        for (int kk = 0; kk < TK; ++kk) {
            float a[8], b[8];
            *(float4*)&a[0] = *(const float4*)&As[kk][ty * 8];
            *(float4*)&a[4] = *(const float4*)&As[kk][ty * 8 + 4];
            *(float4*)&b[0] = *(const float4*)&Bs[kk][tx * 8];
            *(float4*)&b[4] = *(const float4*)&Bs[kk][tx * 8 + 4];
#pragma unroll
            for (int i = 0; i < 8; ++i)
#pragma unroll
                for (int j = 0; j < 8; ++j)
                    acc[i][j] += a[i] * b[j];
        }
    }

#pragma unroll
    for (int i = 0; i < 8; ++i) {
        float* dst = &O[(size_t)(m0 + ty * 8 + i) * Cn + n0 + tx * 8];
        float4 o0 = make_float4(acc[i][0], acc[i][1], acc[i][2], acc[i][3]);
        float4 o1 = make_float4(acc[i][4], acc[i][5], acc[i][6], acc[i][7]);
        *(float4*)&dst[0] = o0;
        *(float4*)&dst[4] = o1;
    }
}

// ---------------------------------------------------------------------------
// Feature sparsify: per 64-elem head vector keep |v| >= 8th-largest |v|.
// One wave per vector; Q,K,V in-place.  3*65536 vectors total.
// ---------------------------------------------------------------------------
__global__ __launch_bounds__(256)
void sparsify_topk(float* __restrict__ Q, float* __restrict__ K,
                   float* __restrict__ V)
{
    const int wid  = (blockIdx.x * 256 + threadIdx.x) >> 6;  // global wave id
    const int lane = threadIdx.x & 63;
    const int tensor = wid >> 16;        // 65536 vectors per tensor
    const int vec    = wid & 65535;
    float* base = (tensor == 0) ? Q : (tensor == 1 ? K : V);

    const size_t off = (size_t)vec * 64 + lane;
    const float v = base[off];
    const float a = fabsf(v);

    int cnt = 0;   // # strictly greater than mine
#pragma unroll
    for (int j = 0; j < 64; ++j) {
        const float aj = __shfl(a, j);
        cnt += (aj > a) ? 1 : 0;
    }
    // kth = min over values with fewer than FKEEP strictly-greater = 8th largest
    float cand = (cnt < FKEEP) ? a : 3.402823466e38f;
#pragma unroll
    for (int o = 32; o; o >>= 1) cand = fminf(cand, __shfl_xor(cand, o));
    base[off] = (a >= cand) ? v : 0.0f;
}

// ---------------------------------------------------------------------------
// Attention core: block = 1024 threads = 16 waves; wave w owns query row
// t = blockIdx.x*16 + w for head (b,h) = blockIdx.y.  K staged in LDS tiles
// of 128 cols (stride 65 -> conflict-free gather).  Scores (u-mapped) live in
// 32 regs/lane (col = i*64+lane).  Exact top-256 via MSB bit-descent.
// ---------------------------------------------------------------------------
__global__ __launch_bounds__(1024)
void attn_kernel(const float* __restrict__ Qm, const float* __restrict__ Km,
                 const float* __restrict__ Vm, float* __restrict__ AO)
{
    __shared__ float ktile[128][65];     // 33.3 KB, pad 65 -> 2-way max (free)
    __shared__ float qval_s[16][64];
    __shared__ int   qidx_s[16][64];

    const int tid  = threadIdx.x;
    const int w    = tid >> 6;
    const int lane = tid & 63;
    const int bh   = blockIdx.y;         // 0..31
    const int b    = bh >> 4;
    const int h    = bh & 15;
    const int tile = blockIdx.x;         // 0..127
    const int t    = tile * 16 + w;
    const size_t rowoff = (size_t)(b * Tn + t) * Cn + h * Dn;
    const size_t kvoff  = (size_t)(b * Tn) * Cn + h * Dn;

    // ---- load + compact sparse q row (fold in 1/sqrt(D)=0.125) ----
    const float qv = Qm[rowoff + lane];
    const unsigned long long nzm = __ballot(qv != 0.0f);
    const int pos = __popcll(nzm & ((1ull << lane) - 1ull));
    if (qv != 0.0f) {
        qval_s[w][pos] = qv * 0.125f;
        qidx_s[w][pos] = lane;
    }
    const int nnz = __popcll(nzm);       // wave-uniform

    unsigned u[32];
#pragma unroll
    for (int i = 0; i < 32; ++i) u[i] = U_NEG_INF;

    const int tmax   = tile * 16 + 15;
    const int ntiles = (tmax >> 7) + 1;  // block-uniform

#pragma unroll
    for (int it = 0; it < 16; ++it) {
        if (it < ntiles) {               // block-uniform branch (barriers OK)
            const int s0 = it << 7;
            __syncthreads();
#pragma unroll
            for (int r = 0; r < 2; ++r) {
                const int f = tid + r * 1024;      // 0..2047
                const int col = f >> 4, q = f & 15;
                const float4 k4 = *(const float4*)&Km[kvoff + (size_t)(s0 + col) * Cn + q * 4];
                ktile[col][q * 4 + 0] = k4.x;
                ktile[col][q * 4 + 1] = k4.y;
                ktile[col][q * 4 + 2] = k4.z;
                ktile[col][q * 4 + 3] = k4.w;
            }
            __syncthreads();
            float sc0 = 0.0f, sc1 = 0.0f;
            for (int m = 0; m < nnz; ++m) {
                const float qm = qval_s[w][m];     // broadcast reads
                const int   qi = qidx_s[w][m];
                sc0 += qm * ktile[lane][qi];       // 2-way bank alias: free
                sc1 += qm * ktile[64 + lane][qi];
            }
            u[2 * it + 0] = (s0 + lane      <= t) ? umap(sc0) : U_NEG_INF;
            u[2 * it + 1] = (s0 + 64 + lane <= t) ? umap(sc1) : U_NEG_INF;
        }
    }

    // ---- exact 256th-largest via bit-descent (rows t<256 keep all) ----
    unsigned cur;
    if (t < KKEEP) {
        cur = U_NEG_INF;
    } else {
        cur = 0u;
#pragma unroll 1
        for (int bit = 31; bit >= 0; --bit) {
            const unsigned test = cur | (1u << bit);
            int c = 0;
#pragma unroll
            for (int i = 0; i < 32; ++i) c += (u[i] >= test) ? 1 : 0;
#pragma unroll
            for (int o = 32; o; o >>= 1) c += __shfl_xor(c, o);
            if (c >= KKEEP) cur = test;
        }
    }

    // ---- softmax over kept entries ----
    unsigned mu = 0u;
#pragma unroll
    for (int i = 0; i < 32; ++i) mu = (u[i] > mu) ? u[i] : mu;
#pragma unroll
    for (int o = 32; o; o >>= 1) {
        const unsigned m2 = __shfl_xor(mu, o);
        mu = (m2 > mu) ? m2 : mu;
    }
    const float fm = uunmap(mu);         // row max (always finite: col 0 <= t)

    float ps = 0.0f;
#pragma unroll
    for (int i = 0; i < 32; ++i) {
        const float f  = uunmap(u[i]);
        const float pv = (u[i] >= cur) ? __expf(f - fm) : 0.0f;  // exp(-inf)=0
        u[i] = __float_as_uint(pv);      // reuse regs for probabilities
        ps += pv;
    }
#pragma unroll
    for (int o = 32; o; o >>= 1) ps += __shfl_xor(ps, o);
    const float inv = 1.0f / ps;         // ps >= 1

    // ---- PV: weighted gather of kept V rows (2-deep load pipeline) ----
    float acc = 0.0f;
    const float* __restrict__ vcol = Vm + kvoff + lane;
#pragma unroll
    for (int i = 0; i < 32; ++i) {
        const float pv = __uint_as_float(u[i]);
        unsigned long long m = __ballot(pv > 0.0f);   // wave-uniform
        const int cb = i * 64;
        while (m) {
            const int l0 = __builtin_ctzll(m); m &= m - 1;
            const float w0 = __shfl(pv, l0);
            const float v0 = vcol[(size_t)(cb + l0) * Cn];
            float w1 = 0.0f, v1 = 0.0f;
            if (m) {
                const int l1 = __builtin_ctzll(m); m &= m - 1;
                w1 = __shfl(pv, l1);
                v1 = vcol[(size_t)(cb + l1) * Cn];
            }
            acc += w0 * v0;
            acc += w1 * v1;
        }
    }
    AO[rowoff + lane] = acc * inv;
}

// ---------------------------------------------------------------------------
extern "C" void kernel_launch(void* const* d_in, const int* in_sizes, int n_in,
                              void* d_out, int out_size, void* d_ws, size_t ws_size,
                              hipStream_t stream)
{
    const float* x  = (const float*)d_in[0];
    const float* Wq = (const float*)d_in[1];
    const float* Wk = (const float*)d_in[2];
    const float* Wv = (const float*)d_in[3];
    const float* Wo = (const float*)d_in[4];
    float* out = (float*)d_out;

    float* Q  = (float*)d_ws;            // 4 buffers x 4194304 floats = 64 MB
    float* K  = Q + (size_t)Mn * Cn;
    float* V  = K + (size_t)Mn * Cn;
    float* AO = V + (size_t)Mn * Cn;

    // 1) Q/K/V projections (fp32)
    gemm_nt_f32<<<dim3(Cn / TN, Mn / TM, 3), 256, 0, stream>>>(
        x, Wq, Wk, Wv, Q, K, V);

    // 2) feature top-8 sparsification, in place
    sparsify_topk<<<dim3(3 * 65536 / 4), 256, 0, stream>>>(Q, K, V);

    // 3) sparse attention core -> AO in [B,T,H,D] (== [B,T,C]) layout
    attn_kernel<<<dim3(Tn / 16, 32), 1024, 0, stream>>>(Q, K, V, AO);

    // 4) output projection (fp32)
    gemm_nt_f32<<<dim3(Cn / TN, Mn / TM, 1), 256, 0, stream>>>(
        AO, Wo, Wo, Wo, out, out, out);
}